// Round 7
// baseline (2701893.164 us; speedup 1.0000x reference)
//
#include <hip/hip_runtime.h>

typedef unsigned short u16;
typedef unsigned int   u32;
typedef unsigned long long u64;
typedef __attribute__((ext_vector_type(8))) short bf16x8;
typedef __attribute__((ext_vector_type(16))) float f32x16;
typedef __attribute__((ext_vector_type(4))) float f32x4;
typedef __attribute__((ext_vector_type(4))) u32 u32x4;

#define T_SEQ 300

// workspace layout (bytes) — all offsets 16B-aligned
#define OFF_WP   0u            // packed A-frag weights bf16: 256 jp * 42 kk * 64 lanes * 16B = 11,010,048
#define OFF_BP   11010048u     // packed bias f32 [512 j][16 g] = 32,768
#define OFF_XB   11042816u     // x bf16 K-slot layout: 300*128*192*2 = 14,745,600
#define OFF_H    25788416u     // h arena bf16: 301 * 128*512 * 2B = 39,452,672
#define OFF_FL   65241088u     // flags[128]=[bq 4][32 jgh] + claim[8] at +128 (144 ints)

__device__ __forceinline__ float bf2f(u16 u){ union { u32 u; float f; } v; v.u = ((u32)u) << 16; return v.f; }
__device__ __forceinline__ u16 f2bf(float f){
  union { float f; u32 u; } v; v.f = f;
  u32 r = v.u + 0x7fffu + ((v.u >> 16) & 1u);
  return (u16)(r >> 16);
}
__device__ __forceinline__ float sigf(float x){ return 1.f / (1.f + __expf(-x)); }
__device__ __forceinline__ float tanh_f(float x){ return 1.f - 2.f / (1.f + __expf(2.f * x)); }

// ---- XCD-local memory ops. Model (validated by r5/r6 behavior): within a
// dispatch the XCD's L2 is the local coherence point; plain stores make a
// dirty L2 line that same-XCD sc0 loads observe; sc1 ops bypass L2 WITHOUT
// invalidating it (r6 bug: sc1 flag store + sc0 poll = stuck stale). ----
__device__ __forceinline__ int ld_flag_sc0(const int* p) {
  int r;
  asm volatile("global_load_dword %0, %1, off sc0\n\ts_waitcnt vmcnt(0)"
               : "=v"(r) : "v"(p) : "memory");
  return r;
}
__device__ __forceinline__ void st_flag_l2(int* p, int v) {
  // plain store: lands dirty in the writer's XCD L2 — visible to same-XCD
  // sc0 pollers. Ordered after h stores by the preceding __syncthreads
  // (vmcnt drain) + same-L2 destination.
  asm volatile("global_store_dword %0, %1, off" :: "v"(p), "v"(v) : "memory");
}
__device__ __forceinline__ void ld_sc0_x4_b4(const u16* p0, const u16* p1,
                                             const u16* p2, const u16* p3,
                                             u32x4& r0, u32x4& r1, u32x4& r2, u32x4& r3) {
  asm volatile(
    "global_load_dwordx4 %0, %4, off sc0\n\t"
    "global_load_dwordx4 %1, %5, off sc0\n\t"
    "global_load_dwordx4 %2, %6, off sc0\n\t"
    "global_load_dwordx4 %3, %7, off sc0\n\t"
    "s_waitcnt vmcnt(0)"
    : "=&v"(r0), "=&v"(r1), "=&v"(r2), "=&v"(r3)
    : "v"(p0), "v"(p1), "v"(p2), "v"(p3) : "memory");
}
__device__ __forceinline__ u32x4 ld_sc0_x4(const u16* p) {
  u32x4 r;
  asm volatile("global_load_dwordx4 %0, %1, off sc0\n\ts_waitcnt vmcnt(0)"
               : "=v"(r) : "v"(p) : "memory");
  return r;
}

// ---------------------------------------------------------------------------
// prep: pack fp32 weights into 32x32x16 MFMA A-operand fragments (gates on the
// M side; acc[reg] = gate reg for j=jp*2+(lane>>5) per lane). Also: bias pack
// [j][16], zero h[0], and EVERY block re-zeroes flags+claim.
// ---------------------------------------------------------------------------
__global__ void prep(const float* __restrict__ Wx, const float* __restrict__ Wh,
                     const float* __restrict__ bg, const float* __restrict__ Wxo,
                     const float* __restrict__ Who, const float* __restrict__ bo,
                     u16* __restrict__ Wp, float* __restrict__ bpack,
                     u16* __restrict__ h0, int* __restrict__ flags)
{
  if (threadIdx.x < 144) flags[threadIdx.x] = 0;   // racing identical stores: benign

  int w = blockIdx.x * 256 + threadIdx.x;          // 0 .. 688127 = 256 jp * 42 kk * 64

  if (w < 8192) {
    u32x4 z = {0u, 0u, 0u, 0u};
    ((u32x4*)h0)[w] = z;                           // zero h[0] (128*512 bf16)
    int j = w >> 4, g = w & 15;
    float bv;
    if (g < 15) { int p = g / 3, t3 = g - p * 3; bv = bg[p * 1536 + t3 * 512 + j]; }
    else bv = bo[j];
    bpack[w] = bv;
  }

  int lane = w & 63, rem = w >> 6;
  int kk = rem % 42, jp = rem / 42;                // jp 0..255
  int m = lane & 31, hi = lane >> 5;
  int jj = (m >> 2) & 1, g = (m & 3) + 4 * (m >> 3);
  int j = jp * 2 + jj;
  union { u16 s[8]; u32x4 v; } o;
  #pragma unroll
  for (int i = 0; i < 8; ++i) {
    int k = kk * 16 + hi * 8 + i;
    float val = 0.f;
    if (g < 15) {
      int p = g / 3, t3 = g - p * 3, col = t3 * 512 + j;
      if (k < 512) val = Wh[(p * 512 + k) * 1536 + col];
      else {
        int s = k - 512, px = s >> 5, cc = (s >> 3) & 3, ii = s & 7;
        int d = (cc < 3) ? cc * 8 + ii : ((ii < 2) ? -1 : 22 + ii);
        if (px == p && d >= 0) val = Wx[(p * 30 + d) * 1536 + col];
      }
    } else {
      if (k < 512) val = Who[k * 512 + j];
      else {
        int s = k - 512, px = s >> 5, cc = (s >> 3) & 3, ii = s & 7;
        int d = (cc < 3) ? cc * 8 + ii : ((ii < 2) ? -1 : 22 + ii);
        if (d >= 0) val = Wxo[(px * 30 + d) * 512 + j];
      }
    }
    o.s[i] = f2bf(val);
  }
  *(u32x4*)(Wp + ((size_t)(jp * 42 + kk) * 64 + lane) * 8) = o.v;
}

// ---------------------------------------------------------------------------
// prep_x: fp32 x [5][128][300][30] -> bf16 xb[t][bglob][slot] (slot 0..191,
// slots 160..191 zero pad). One thread = one 8-slot chunk (16B store).
// ---------------------------------------------------------------------------
__global__ void prep_x(const float* __restrict__ x, u16* __restrict__ xb)
{
  int w = blockIdx.x * 256 + threadIdx.x;          // 0 .. 921599
  int cx = w % 24, rem = w / 24;
  int bglob = rem % 128, t = rem / 128;
  union { u16 s[8]; u32x4 v; } o;
  int s0 = cx << 3;
  if (s0 >= 160) {
    u32x4 z = {0u, 0u, 0u, 0u}; o.v = z;
  } else {
    int p = s0 >> 5, cc = (s0 >> 3) & 3;
    const float* row = x + ((size_t)(p * 128 + bglob) * 300 + t) * 30;
    #pragma unroll
    for (int i = 0; i < 8; ++i) {
      int d = (cc < 3) ? cc * 8 + i : 22 + i;
      o.s[i] = f2bf(row[d]);
    }
  }
  *(u32x4*)(xb + (size_t)w * 8) = o.v;
}

// XCD-local readiness wait: lanes poll the quarter's 32 flags at local L2
// (sc0). Bounded so a placement pathology fails fast instead of hanging.
__device__ __forceinline__ void wait_flags32(const int* f, int t)
{
  const int* p = f + (threadIdx.x & 31);
  for (int it = 0; it < (1 << 17); ++it) {
    int v = ld_flag_sc0(p);
    if (__all(v >= t)) return;
  }
}

// ---------------------------------------------------------------------------
// Persistent part-LSTM, gate-in-lane + XCD-local sync domains.
// NORMAL launch, 512 blocks x 512 threads. Each block reads HW_REG_XCC_ID and
// claims a slot on its XCD; XCDs 0..3 host batch-quarters 0..3 (32 blocks x
// 16 j-cols each); all other blocks exit. h publish = plain stores (dirty in
// the XCD-shared L2); h reload = sc0 loads; flags = plain store + sc0 poll.
// ---------------------------------------------------------------------------
__global__ void __launch_bounds__(512, 2)
plstm(const u16* __restrict__ xb, const u16* __restrict__ Wp,
      const float* __restrict__ bpack, u16* hall, int* flags,
      const float* __restrict__ fcw, const float* __restrict__ fcb,
      float* __restrict__ out)
{
  __shared__ __align__(16) u16 Hsh[32 * 512];   // 32 KB: h rows [b][64 chunks] (xor-swizzled)
  __shared__ __align__(16) u16 Xsh[32 * 256];   // 16 KB: x rows [b][32 chunks] (xor-swizzled)
  __shared__ __align__(16) u16 hbuf[32 * 16];   // 1 KB: h publish staging
  __shared__ int sslot;

  const int tid  = threadIdx.x;
  const int lane = tid & 63;
  const int wv   = tid >> 6;          // 8 waves
  const int n    = lane & 31;         // batch row within quarter
  const int hi   = lane >> 5;         // k-half / j-parity

  // ---- XCD claim: quarter q lives on XCD q ----
  int xcc = __builtin_amdgcn_s_getreg((7 << 11) | 20) & 7;   // HW_REG_XCC_ID
  int* claim = flags + 128;
  if (xcc >= 4) return;
  if (tid == 0)
    sslot = __hip_atomic_fetch_add(&claim[xcc], 1, __ATOMIC_RELAXED, __HIP_MEMORY_SCOPE_AGENT);
  __syncthreads();
  const int slot = sslot;
  if (slot >= 32) return;

  const int bq  = xcc;                // batch quarter
  const int jgh = slot;               // 16-col j-group
  const int jp  = jgh * 8 + wv;       // j-pair 0..255
  const int j   = jp * 2 + hi;        // this lane's hidden col
  int* myflags = flags + bq * 32;

  // resident A-fragments (weights), 42 ksteps x 4 regs (AGPR/VGPR unified)
  bf16x8 afr[42];
  {
    const u16* wpb = Wp + ((size_t)jp * 42 * 64 + lane) * 8;
    #pragma unroll
    for (int kk = 0; kk < 42; ++kk)
      afr[kk] = *(const bf16x8*)(wpb + kk * 512);
  }
  float bias[16];
  #pragma unroll
  for (int i = 0; i < 4; ++i)
    *(f32x4*)(bias + i * 4) = *(const f32x4*)(bpack + j * 16 + i * 4);

  float cst[5] = {0.f, 0.f, 0.f, 0.f, 0.f};

  for (int t = 0; t < T_SEQ; ++t) {
    // ---- stage x[t] rows (own quarter) into LDS, chunk-XOR swizzle ----
    {
      const u16* xsrc = xb + (size_t)(t * 128 + bq * 32) * 192;
      #pragma unroll
      for (int i = 0; i < 2; ++i) {
        int c = tid + (i << 9);           // valid < 768 = 32 rows * 24 chunks
        if (c < 768) {
          int b = c / 24, cx = c - b * 24;
          u32x4 v = *(const u32x4*)(xsrc + b * 192 + (cx << 3));
          *(u32x4*)(Xsh + (b << 8) + (((cx ^ b) & 31) << 3)) = v;
        }
      }
    }
    __syncthreads();

    f32x16 acc;
    #pragma unroll
    for (int i = 0; i < 16; ++i) acc[i] = 0.f;

    // ---- K-loop, x part (no h dependency — absorbs inter-block jitter) ----
    #pragma unroll
    for (int kx = 0; kx < 10; ++kx) {
      int c = kx * 2 + hi;                // chunk 0..19
      bf16x8 bf = *(const bf16x8*)(Xsh + (n << 8) + (((c ^ n) & 31) << 3));
      acc = __builtin_amdgcn_mfma_f32_32x32x16_bf16(afr[32 + kx], bf, acc, 0, 0, 0);
    }

    // ---- wait until h(t) published by all 32 blocks of my quarter ----
    wait_flags32(myflags, t);

    // ---- stage h[t] rows (own quarter) into LDS via sc0 (local L2) ----
    {
      const u16* hsrc = hall + (size_t)t * 65536 + ((bq * 32) << 9);
      int c0 = tid, c1 = tid + 512, c2 = tid + 1024, c3 = tid + 1536;
      const u16* p0 = hsrc + ((c0 >> 6) << 9) + ((c0 & 63) << 3);
      const u16* p1 = hsrc + ((c1 >> 6) << 9) + ((c1 & 63) << 3);
      const u16* p2 = hsrc + ((c2 >> 6) << 9) + ((c2 & 63) << 3);
      const u16* p3 = hsrc + ((c3 >> 6) << 9) + ((c3 & 63) << 3);
      u32x4 v0, v1, v2, v3;
      ld_sc0_x4_b4(p0, p1, p2, p3, v0, v1, v2, v3);
      #pragma unroll
      for (int i = 0; i < 4; ++i) {
        int c = tid + (i << 9);
        int b = c >> 6, cx = c & 63;
        int phys = (cx & 32) | ((cx ^ b) & 31);
        u32x4 v = (i == 0) ? v0 : (i == 1) ? v1 : (i == 2) ? v2 : v3;
        *(u32x4*)(Hsh + (b << 9) + (phys << 3)) = v;
      }
    }
    __syncthreads();

    // ---- K-loop, hidden part ----
    #pragma unroll
    for (int kk = 0; kk < 32; ++kk) {
      int c = kk * 2 + hi;                // chunk 0..63
      int phys = (c & 32) | ((c ^ n) & 31);
      bf16x8 bf = *(const bf16x8*)(Hsh + (n << 9) + (phys << 3));
      acc = __builtin_amdgcn_mfma_f32_32x32x16_bf16(afr[kk], bf, acc, 0, 0, 0);
    }

    // ---- per-lane elementwise: acc[g] = gate g for (j, b) ----
    float cs = 0.f;
    #pragma unroll
    for (int p = 0; p < 5; ++p) {
      float iv = acc[p * 3 + 0] + bias[p * 3 + 0];
      float fv = acc[p * 3 + 1] + bias[p * 3 + 1];
      float gv = acc[p * 3 + 2] + bias[p * 3 + 2];
      cst[p] = sigf(fv) * cst[p] + sigf(iv) * tanh_f(gv);
      cs += cst[p];
    }
    float hv = sigf(acc[15] + bias[15]) * tanh_f(cs);

    // ---- publish h(t+1): LDS transpose -> plain 16B stores (local L2) ----
    hbuf[(n << 4) + (wv << 1) + hi] = f2bf(hv);
    __syncthreads();
    if (tid < 64) {
      int row = tid >> 1, half = tid & 1;
      u32x4 v = *(const u32x4*)(hbuf + (row << 4) + (half << 3));
      *(u32x4*)(hall + (size_t)(t + 1) * 65536
                + (size_t)(bq * 32 + row) * 512 + (jgh << 4) + (half << 3)) = v;
    }
    __syncthreads();                      // drains vmcnt -> h(t+1) in local L2
    if (tid == 0)
      st_flag_l2(&myflags[jgh], t + 1);
  }

  // ---- classifier + log_softmax: slots 0..15 do 2 rows of own quarter ----
  if (slot >= 16) return;
  wait_flags32(myflags, T_SEQ);
  __syncthreads();
  const u16* hT = hall + (size_t)T_SEQ * 65536 + (size_t)(bq * 32 + slot * 2) * 512;
  if (tid < 128) {                        // stage 2 rows (2 KB) via sc0
    u32x4 v = ld_sc0_x4(hT + ((tid >> 6) << 9) + ((tid & 63) << 3));
    *(u32x4*)(Hsh + tid * 8) = v;
  }
  __syncthreads();
  float* fsh = (float*)Xsh;
  for (int r = 0; r < 2; ++r) {
    int row = bq * 32 + slot * 2 + r;
    int ks = tid >> 6, c = tid & 63;      // 8 K-slices of 64
    float s = 0.f;
    if (c < 60) {
      const u16* hr = Hsh + (r << 9) + ks * 64;
      const float* wr = fcw + (size_t)(ks * 64) * 60 + c;
      #pragma unroll 8
      for (int k = 0; k < 64; ++k) s += bf2f(hr[k]) * wr[k * 60];
    }
    __syncthreads();
    fsh[ks * 64 + c] = s;
    __syncthreads();
    if (tid < 60) {
      float lg = fcb[tid];
      #pragma unroll
      for (int i = 0; i < 8; ++i) lg += fsh[i * 64 + tid];
      fsh[512 + tid] = lg;
    }
    __syncthreads();
    if (tid == 0) {
      float mx = -1e30f;
      for (int i = 0; i < 60; ++i) mx = fmaxf(mx, fsh[512 + i]);
      float sm = 0.f;
      for (int i = 0; i < 60; ++i) sm += __expf(fsh[512 + i] - mx);
      fsh[576] = mx + __logf(sm);
    }
    __syncthreads();
    if (tid < 60) out[row * 60 + tid] = fsh[512 + tid] - fsh[576];
    __syncthreads();
  }
}

extern "C" void kernel_launch(void* const* d_in, const int* in_sizes, int n_in,
                              void* d_out, int out_size, void* d_ws, size_t ws_size,
                              hipStream_t stream)
{
  const float* xin = (const float*)d_in[0];   // [5][128][300][30]
  const float* Wx  = (const float*)d_in[1];   // [5][30][1536]
  const float* Wh  = (const float*)d_in[2];   // [5][512][1536]
  const float* bg  = (const float*)d_in[3];   // [5][1536]
  const float* Wxo = (const float*)d_in[4];   // [150][512]
  const float* Who = (const float*)d_in[5];   // [512][512]
  const float* bo  = (const float*)d_in[6];   // [512]
  const float* fcw = (const float*)d_in[7];   // [512][60]
  const float* fcb = (const float*)d_in[8];   // [60]
  float* out = (float*)d_out;                 // [128][60]

  char* ws = (char*)d_ws;
  u16*   Wp    = (u16*)(ws + OFF_WP);
  float* bpack = (float*)(ws + OFF_BP);
  u16*   xb    = (u16*)(ws + OFF_XB);
  u16*   hall  = (u16*)(ws + OFF_H);
  int*   flags = (int*)(ws + OFF_FL);

  hipLaunchKernelGGL(prep, dim3(2688), dim3(256), 0, stream,
                     Wx, Wh, bg, Wxo, Who, bo, Wp, bpack, hall, flags);
  hipLaunchKernelGGL(prep_x, dim3(3600), dim3(256), 0, stream, xin, xb);

  hipLaunchKernelGGL(plstm, dim3(512), dim3(512), 0, stream,
                     xb, Wp, bpack, hall, flags, fcw, fcb, out);
}

// Round 9
// 2002.413 us; speedup vs baseline: 1349.3184x; 1349.3184x over previous
//
#include <hip/hip_runtime.h>

typedef unsigned short u16;
typedef unsigned int   u32;
typedef unsigned long long u64;
typedef __attribute__((ext_vector_type(8))) short bf16x8;
typedef __attribute__((ext_vector_type(16))) float f32x16;
typedef __attribute__((ext_vector_type(4))) float f32x4;
typedef __attribute__((ext_vector_type(4))) u32 u32x4;

#define T_SEQ 300

// workspace layout (bytes) — all offsets 16B-aligned
#define OFF_WP   0u            // packed A-frag weights bf16: 256 jp * 42 kk * 64 lanes * 16B = 11,010,048
#define OFF_BP   11010048u     // packed bias f32 [512 j][16 g] = 32,768
#define OFF_XB   11042816u     // x bf16 K-slot layout: 300*128*192*2 = 14,745,600
#define OFF_H    25788416u     // h arena bf16: 301 * 128*512 * 2B = 39,452,672
#define OFF_FL   65241088u     // flags[128] = [bq 4][32 jgh]

__device__ __forceinline__ float bf2f(u16 u){ union { u32 u; float f; } v; v.u = ((u32)u) << 16; return v.f; }
__device__ __forceinline__ u16 f2bf(float f){
  union { float f; u32 u; } v; v.f = f;
  u32 r = v.u + 0x7fffu + ((v.u >> 16) & 1u);
  return (u16)(r >> 16);
}
__device__ __forceinline__ float sigf(float x){ return 1.f / (1.f + __expf(-x)); }
__device__ __forceinline__ float tanh_f(float x){ return 1.f - 2.f / (1.f + __expf(2.f * x)); }

// ---------------------------------------------------------------------------
// Sync model (settled after r5-r8 experiments): ONLY the fully agent-scope
// protocol is reliable on this machine — atomic stores/loads at AGENT scope
// (IF$ coherence point) for h publish + flags, plain loads for h reload at
// addresses that rotate every step (never re-read before their unique write).
// XCD-local (L2/sc0) flag polling is falsified: sc0 polls can be served by
// per-CU L1 and never observe remote updates (r6/r7 timeouts, r8 replay
// nondeterminism). Polls are UNBOUNDED — a timeout is a correctness hole.
// ---------------------------------------------------------------------------

// prep: pack fp32 weights into 32x32x16 MFMA A-operand fragments (gates on the
// M side; acc[reg] = gate reg for j=jp*2+(lane>>5) per lane). Also: bias pack
// [j][16], zero h[0], reset flags.
__global__ void prep(const float* __restrict__ Wx, const float* __restrict__ Wh,
                     const float* __restrict__ bg, const float* __restrict__ Wxo,
                     const float* __restrict__ Who, const float* __restrict__ bo,
                     u16* __restrict__ Wp, float* __restrict__ bpack,
                     u16* __restrict__ h0, int* __restrict__ flags)
{
  int w = blockIdx.x * 256 + threadIdx.x;     // 0 .. 688127 = 256 jp * 42 kk * 64

  if (w < 8192) {
    u32x4 z = {0u, 0u, 0u, 0u};
    ((u32x4*)h0)[w] = z;                      // zero h[0] (128*512 bf16)
    int j = w >> 4, g = w & 15;
    float bv;
    if (g < 15) { int p = g / 3, t3 = g - p * 3; bv = bg[p * 1536 + t3 * 512 + j]; }
    else bv = bo[j];
    bpack[w] = bv;
  }
  if (w < 128) flags[w] = 0;

  int lane = w & 63, rem = w >> 6;
  int kk = rem % 42, jp = rem / 42;           // jp 0..255
  int m = lane & 31, hi = lane >> 5;
  int jj = (m >> 2) & 1, g = (m & 3) + 4 * (m >> 3);
  int j = jp * 2 + jj;
  union { u16 s[8]; u32x4 v; } o;
  #pragma unroll
  for (int i = 0; i < 8; ++i) {
    int k = kk * 16 + hi * 8 + i;
    float val = 0.f;
    if (g < 15) {
      int p = g / 3, t3 = g - p * 3, col = t3 * 512 + j;
      if (k < 512) val = Wh[(p * 512 + k) * 1536 + col];
      else {
        int s = k - 512, px = s >> 5, cc = (s >> 3) & 3, ii = s & 7;
        int d = (cc < 3) ? cc * 8 + ii : ((ii < 2) ? -1 : 22 + ii);
        if (px == p && d >= 0) val = Wx[(p * 30 + d) * 1536 + col];
      }
    } else {
      if (k < 512) val = Who[k * 512 + j];
      else {
        int s = k - 512, px = s >> 5, cc = (s >> 3) & 3, ii = s & 7;
        int d = (cc < 3) ? cc * 8 + ii : ((ii < 2) ? -1 : 22 + ii);
        if (d >= 0) val = Wxo[(px * 30 + d) * 512 + j];
      }
    }
    o.s[i] = f2bf(val);
  }
  *(u32x4*)(Wp + ((size_t)(jp * 42 + kk) * 64 + lane) * 8) = o.v;
}

// prep_x: fp32 x [5][128][300][30] -> bf16 xb[t][bglob][slot] (slot 0..191,
// slots 160..191 zero pad). One thread = one 8-slot chunk (16B store).
__global__ void prep_x(const float* __restrict__ x, u16* __restrict__ xb)
{
  int w = blockIdx.x * 256 + threadIdx.x;     // 0 .. 921599
  int cx = w % 24, rem = w / 24;
  int bglob = rem % 128, t = rem / 128;
  union { u16 s[8]; u32x4 v; } o;
  int s0 = cx << 3;
  if (s0 >= 160) {
    u32x4 z = {0u, 0u, 0u, 0u}; o.v = z;
  } else {
    int p = s0 >> 5, cc = (s0 >> 3) & 3;
    const float* row = x + ((size_t)(p * 128 + bglob) * 300 + t) * 30;
    #pragma unroll
    for (int i = 0; i < 8; ++i) {
      int d = (cc < 3) ? cc * 8 + i : 22 + i;
      o.s[i] = f2bf(row[d]);
    }
  }
  *(u32x4*)(xb + (size_t)w * 8) = o.v;
}

// Agent-scope readiness wait — called by ONE wave only (contention control:
// r5 had 1024 concurrent wave-polls hammering 128B of IF$; now 128).
__device__ __forceinline__ void wait_flags32(const int* f, int t)
{
  const int* p = f + (threadIdx.x & 31);
  for (;;) {
    int v = __hip_atomic_load(p, __ATOMIC_RELAXED, __HIP_MEMORY_SCOPE_AGENT);
    if (__all(v >= t)) return;
  }
}

// ---------------------------------------------------------------------------
// Persistent part-LSTM, gate-in-lane formulation (proven r5 structure).
// 128 blocks x 512 threads (cooperative; 2 waves/SIMD). Block = (bq: batch
// quarter) x (jgh: 16 hidden cols). Wave = one 32x32x16-MFMA chain: M=32
// (16 gates x 2 j), N=32 batch rows, K=672; weights resident in registers.
// Changes vs r5: (1) only wave 0 polls, others park at a barrier;
// (2) wave 0 alone publishes h + release-stores the flag (one less barrier,
// waves 1-7 run ahead into step t+1 x-staging).
// ---------------------------------------------------------------------------
__global__ void __launch_bounds__(512, 2)
plstm(const u16* __restrict__ xb, const u16* __restrict__ Wp,
      const float* __restrict__ bpack, u16* hall, int* flags,
      const float* __restrict__ fcw, const float* __restrict__ fcb,
      float* __restrict__ out)
{
  __shared__ __align__(16) u16 Hsh[32 * 512];   // 32 KB: h rows [b][64 chunks] (xor-swizzled)
  __shared__ __align__(16) u16 Xsh[32 * 256];   // 16 KB: x rows [b][32 chunks] (xor-swizzled)
  __shared__ __align__(16) u16 hbuf[32 * 16];   // 1 KB: h publish staging

  const int tid  = threadIdx.x;
  const int lane = tid & 63;
  const int wv   = tid >> 6;          // 8 waves
  const int n    = lane & 31;         // batch row within quarter
  const int hi   = lane >> 5;         // k-half / j-parity
  const int bq   = blockIdx.x >> 5;   // 0..3
  const int jgh  = blockIdx.x & 31;   // 0..31 (16 j each)
  const int jp   = jgh * 8 + wv;      // j-pair 0..255
  const int j    = jp * 2 + hi;       // this lane's hidden col
  int* myflags = flags + bq * 32;

  // resident A-fragments (weights), 42 ksteps x 4 regs
  bf16x8 afr[42];
  {
    const u16* wpb = Wp + ((size_t)jp * 42 * 64 + lane) * 8;
    #pragma unroll
    for (int kk = 0; kk < 42; ++kk)
      afr[kk] = *(const bf16x8*)(wpb + kk * 512);
  }
  float bias[16];
  #pragma unroll
  for (int i = 0; i < 4; ++i)
    *(f32x4*)(bias + i * 4) = *(const f32x4*)(bpack + j * 16 + i * 4);

  float cst[5] = {0.f, 0.f, 0.f, 0.f, 0.f};

  for (int t = 0; t < T_SEQ; ++t) {
    // ---- stage x[t] rows (own quarter) into LDS, chunk-XOR swizzle ----
    {
      const u16* xsrc = xb + (size_t)(t * 128 + bq * 32) * 192;
      #pragma unroll
      for (int i = 0; i < 2; ++i) {
        int c = tid + (i << 9);           // valid < 768 = 32 rows * 24 chunks
        if (c < 768) {
          int b = c / 24, cx = c - b * 24;
          u32x4 v = *(const u32x4*)(xsrc + b * 192 + (cx << 3));
          *(u32x4*)(Xsh + (b << 8) + (((cx ^ b) & 31) << 3)) = v;
        }
      }
    }
    __syncthreads();

    f32x16 acc;
    #pragma unroll
    for (int i = 0; i < 16; ++i) acc[i] = 0.f;

    // ---- K-loop, x part (no h dependency — absorbs inter-block jitter) ----
    #pragma unroll
    for (int kx = 0; kx < 10; ++kx) {
      int c = kx * 2 + hi;                // chunk 0..19
      bf16x8 bf = *(const bf16x8*)(Xsh + (n << 8) + (((c ^ n) & 31) << 3));
      acc = __builtin_amdgcn_mfma_f32_32x32x16_bf16(afr[32 + kx], bf, acc, 0, 0, 0);
    }

    // ---- wave 0 polls; everyone else parks at the barrier ----
    if (wv == 0) wait_flags32(myflags, t);
    __syncthreads();

    // ---- stage h[t] rows (own quarter) into LDS, chunk-XOR swizzle ----
    {
      const u16* hsrc = hall + (size_t)t * 65536 + ((bq * 32) << 9);
      #pragma unroll
      for (int i = 0; i < 4; ++i) {
        int c = tid + (i << 9);           // 0..2047 = 32 rows * 64 chunks
        int b = c >> 6, cx = c & 63;
        u32x4 v = *(const u32x4*)(hsrc + (b << 9) + (cx << 3));
        int phys = (cx & 32) | ((cx ^ b) & 31);
        *(u32x4*)(Hsh + (b << 9) + (phys << 3)) = v;
      }
    }
    __syncthreads();

    // ---- K-loop, hidden part ----
    #pragma unroll
    for (int kk = 0; kk < 32; ++kk) {
      int c = kk * 2 + hi;                // chunk 0..63
      int phys = (c & 32) | ((c ^ n) & 31);
      bf16x8 bf = *(const bf16x8*)(Hsh + (n << 9) + (phys << 3));
      acc = __builtin_amdgcn_mfma_f32_32x32x16_bf16(afr[kk], bf, acc, 0, 0, 0);
    }

    // ---- per-lane elementwise: acc[g] = gate g for (j, b) ----
    float cs = 0.f;
    #pragma unroll
    for (int p = 0; p < 5; ++p) {
      float iv = acc[p * 3 + 0] + bias[p * 3 + 0];
      float fv = acc[p * 3 + 1] + bias[p * 3 + 1];
      float gv = acc[p * 3 + 2] + bias[p * 3 + 2];
      cst[p] = sigf(fv) * cst[p] + sigf(iv) * tanh_f(gv);
      cs += cst[p];
    }
    float hv = sigf(acc[15] + bias[15]) * tanh_f(cs);

    // ---- publish h(t+1): transpose via LDS; wave 0 stores + flags ----
    hbuf[(n << 4) + (wv << 1) + hi] = f2bf(hv);
    __syncthreads();
    if (wv == 0) {
      int row = lane >> 1, half = lane & 1;
      const u16* src = hbuf + (row << 4) + (half << 3);
      u64 v0 = *(const u64*)(src);
      u64 v1 = *(const u64*)(src + 4);
      u64* dst = (u64*)(hall + (size_t)(t + 1) * 65536
                        + (size_t)(bq * 32 + row) * 512 + (jgh << 4) + (half << 3));
      __hip_atomic_store(dst,     v0, __ATOMIC_RELAXED, __HIP_MEMORY_SCOPE_AGENT);
      __hip_atomic_store(dst + 1, v1, __ATOMIC_RELAXED, __HIP_MEMORY_SCOPE_AGENT);
      if (lane == 0)   // release: drains the wave's h stores before the flag
        __hip_atomic_store(&myflags[jgh], t + 1, __ATOMIC_RELEASE, __HIP_MEMORY_SCOPE_AGENT);
    }
    // no trailing barrier: waves 1-7 proceed to stage x[t+1]; hbuf isn't
    // rewritten until after the NEXT wait (which requires our flag).
  }

  // ---- classifier + log_softmax: blocks 0..63 do 2 batch rows each ----
  if (blockIdx.x >= 64) return;
  if (wv == 0) {
    for (;;) {
      int v0 = __hip_atomic_load(&flags[lane],      __ATOMIC_RELAXED, __HIP_MEMORY_SCOPE_AGENT);
      int v1 = __hip_atomic_load(&flags[64 + lane], __ATOMIC_RELAXED, __HIP_MEMORY_SCOPE_AGENT);
      if (__all(min(v0, v1) >= T_SEQ)) break;
    }
  }
  __syncthreads();
  float* fsh = (float*)Xsh;
  const u16* hT = hall + (size_t)T_SEQ * 65536;
  for (int r = 0; r < 2; ++r) {
    int row = blockIdx.x * 2 + r;
    int ks = tid >> 6, c = tid & 63;      // 8 K-slices of 64
    float s = 0.f;
    if (c < 60) {
      const u16* hr = hT + row * 512 + ks * 64;
      const float* wr = fcw + (size_t)(ks * 64) * 60 + c;
      #pragma unroll 8
      for (int k = 0; k < 64; ++k) s += bf2f(hr[k]) * wr[k * 60];
    }
    __syncthreads();
    fsh[ks * 64 + c] = s;
    __syncthreads();
    if (tid < 60) {
      float lg = fcb[tid];
      #pragma unroll
      for (int i = 0; i < 8; ++i) lg += fsh[i * 64 + tid];
      fsh[512 + tid] = lg;
    }
    __syncthreads();
    if (tid == 0) {
      float mx = -1e30f;
      for (int i = 0; i < 60; ++i) mx = fmaxf(mx, fsh[512 + i]);
      float sm = 0.f;
      for (int i = 0; i < 60; ++i) sm += __expf(fsh[512 + i] - mx);
      fsh[576] = mx + __logf(sm);
    }
    __syncthreads();
    if (tid < 60) out[row * 60 + tid] = fsh[512 + tid] - fsh[576];
    __syncthreads();
  }
}

extern "C" void kernel_launch(void* const* d_in, const int* in_sizes, int n_in,
                              void* d_out, int out_size, void* d_ws, size_t ws_size,
                              hipStream_t stream)
{
  const float* xin = (const float*)d_in[0];   // [5][128][300][30]
  const float* Wx  = (const float*)d_in[1];   // [5][30][1536]
  const float* Wh  = (const float*)d_in[2];   // [5][512][1536]
  const float* bg  = (const float*)d_in[3];   // [5][1536]
  const float* Wxo = (const float*)d_in[4];   // [150][512]
  const float* Who = (const float*)d_in[5];   // [512][512]
  const float* bo  = (const float*)d_in[6];   // [512]
  const float* fcw = (const float*)d_in[7];   // [512][60]
  const float* fcb = (const float*)d_in[8];   // [60]
  float* out = (float*)d_out;                 // [128][60]

  char* ws = (char*)d_ws;
  u16*   Wp    = (u16*)(ws + OFF_WP);
  float* bpack = (float*)(ws + OFF_BP);
  u16*   xb    = (u16*)(ws + OFF_XB);
  u16*   hall  = (u16*)(ws + OFF_H);
  int*   flags = (int*)(ws + OFF_FL);

  hipLaunchKernelGGL(prep, dim3(2688), dim3(256), 0, stream,
                     Wx, Wh, bg, Wxo, Who, bo, Wp, bpack, hall, flags);
  hipLaunchKernelGGL(prep_x, dim3(3600), dim3(256), 0, stream, xin, xb);

  void* args[] = { (void*)&xb, (void*)&Wp, (void*)&bpack, (void*)&hall,
                   (void*)&flags, (void*)&fcw, (void*)&fcb, (void*)&out };
  hipLaunchCooperativeKernel((void*)plstm, dim3(128), dim3(512), args, 0, stream);
}